// Round 19
// baseline (207.886 us; speedup 1.0000x reference)
//
#include <hip/hip_runtime.h>
#include <hip/hip_bf16.h>

// MoE expert pool: E=8, D=512, H=2048, M=8192 tokens, top-2 routing.
// R19 = R18 + memset dispatch eliminated: prep block 0 computes cnt[8]
// single-block (plain stores, no zero-init needed) and zeroes fillc.
// 5 dispatches: prep -> fill -> gemm1 -> gemm2 -> comb.
// gemm1: 128Mx64N dual-B BK32/32KB 2-phase dbuf (empirical fixed point),
// 2D grid N-slice L2 locality. gemm2: XCD-bijective, bf16 gout. A-S gelu.

#define NEXP 8
#define DIM 512
#define HID 2048
#define MTOK 8192
#define PMAX (2*MTOK)
#define TM 128
#define MT 144

typedef __bf16 bf16;
typedef __bf16 bf16x8 __attribute__((ext_vector_type(8)));
typedef float  f32x4  __attribute__((ext_vector_type(4)));

#define WAITVM(N) asm volatile("s_waitcnt vmcnt(" #N ")" ::: "memory")
#define SCHED0    __builtin_amdgcn_sched_barrier(0)
#define BAR       __builtin_amdgcn_s_barrier

__device__ __forceinline__ void gload16(const bf16* g, bf16* l) {
  __builtin_amdgcn_global_load_lds(
      (const __attribute__((address_space(1))) void*)g,
      (__attribute__((address_space(3))) void*)l, 16, 0, 0);
}

// exact-gelu via Abramowitz-Stegun 7.1.26 erf (validated R10/R12).
__device__ __forceinline__ float gelu_f(float x){
  float s = x * 0.70710678118654752f;
  float a = fabsf(s);
  float t = 1.0f / fmaf(0.3275911f, a, 1.0f);
  float p = t*(0.254829592f + t*(-0.284496736f + t*(1.421413741f +
            t*(-1.453152027f + t*1.061405429f))));
  float er = 1.0f - p*__expf(-s*s);
  er = copysignf(er, s);
  return 0.5f*x*(1.0f + er);
}

// inline tile map: tile T -> (row0, nrows) from cnt[8] (validated R17/R18).
__device__ __forceinline__ bool tile_map(const int* __restrict__ cnt, int T,
                                         int& row0, int& nrows) {
  int sb = 0, stt = 0; bool ok = false;
#pragma unroll
  for (int q=0; q<NEXP; q++){
    int c = cnt[q];
    int nt = (c + TM-1)/TM;
    if (!ok && T >= stt && T < stt+nt){
      int k = T - stt;
      row0 = sb + k*TM;
      int nr = c - k*TM; if (nr > TM) nr = TM;
      nrows = nr; ok = true;
    }
    stt += nt; sb += c;
  }
  return ok;
}

// expert of slot row0 (prefix search, validated R17/R18).
__device__ __forceinline__ int expert_of(const int* __restrict__ cnt, int row0){
  int e = 0, b2 = 0;
#pragma unroll
  for (int q=0;q<NEXP;q++){ if (row0 >= b2 && row0 < b2+cnt[q]) e = q; b2 += cnt[q]; }
  return e;
}

// ---- merged prep, 10241 blocks ----
// b==0: single-block count (plain stores; zero-init-free) + zero fillc
// b in [1,4096]: cvt_x | [4097,8192]: WgWv tcvt | [8193,10240]: Wo tcvt
__global__ __launch_bounds__(256) void k_prep(const float* __restrict__ tokens,
    bf16* __restrict__ Xb,
    const float* __restrict__ Wg, const float* __restrict__ Wv,
    const float* __restrict__ Wo,
    bf16* __restrict__ WgT, bf16* __restrict__ WvT, bf16* __restrict__ WoT,
    const float* __restrict__ disp, int* __restrict__ cnt,
    int* __restrict__ fillc) {
  __shared__ __align__(16) bf16 t[64][72];   // row stride 144B (16B-multiple)
  __shared__ int lc[NEXP];
  const int b = blockIdx.x, tid = threadIdx.x;

  if (b == 0) {                         // ---- count ALL tokens, one block ----
    if (tid < NEXP) lc[tid] = 0;
    __syncthreads();
#pragma unroll 4
    for (int it=0; it<MTOK/256; ++it){
      int m = it*256 + tid;
      float4 d0 = *(const float4*)&disp[(size_t)m*NEXP];
      float4 d1 = *(const float4*)&disp[(size_t)m*NEXP+4];
      if (d0.x>0.f) atomicAdd(&lc[0],1);
      if (d0.y>0.f) atomicAdd(&lc[1],1);
      if (d0.z>0.f) atomicAdd(&lc[2],1);
      if (d0.w>0.f) atomicAdd(&lc[3],1);
      if (d1.x>0.f) atomicAdd(&lc[4],1);
      if (d1.y>0.f) atomicAdd(&lc[5],1);
      if (d1.z>0.f) atomicAdd(&lc[6],1);
      if (d1.w>0.f) atomicAdd(&lc[7],1);
    }
    __syncthreads();
    if (tid < NEXP) cnt[tid] = lc[tid];          // plain store
    if (tid >= NEXP && tid < 2*NEXP) fillc[tid-NEXP] = 0;
    return;
  }
  if (b <= 4096) {                      // ---- fp32 -> bf16 tokens ----
    int i = (b-1)*256 + tid;            // n4 = 1048576 = 4096*256 exact
    float4 v = ((const float4* __restrict__)tokens)[i];
    bf16 o[4];
    o[0]=(bf16)v.x; o[1]=(bf16)v.y; o[2]=(bf16)v.z; o[3]=(bf16)v.w;
    *(uint2*)&Xb[(size_t)i*4] = *(uint2*)o;
    return;
  }
  {                                     // ---- transpose+convert ----
    const float* pin; bf16* pout; int R, C, c0, r0;
    if (b <= 8192) {                    // WgWv: (32,8,16), R=DIM, C=HID
      int u = b - 4097;
      int bx = u&31, by = (u>>5)&7, z = u>>8;
      int e = z & (NEXP-1);
      pin  = ((z < NEXP) ? Wg : Wv) + (size_t)e*DIM*HID;
      pout = ((z < NEXP) ? WgT : WvT) + (size_t)e*DIM*HID;
      R = DIM; C = HID; c0 = bx*64; r0 = by*64;
    } else {                            // Wo: (8,32,8), R=HID, C=DIM
      int u = b - 8193;
      int bx = u&7, by = (u>>3)&31, z = u>>8;
      pin  = Wo  + (size_t)z*HID*DIM;
      pout = WoT + (size_t)z*HID*DIM;
      R = HID; C = DIM; c0 = bx*64; r0 = by*64;
    }
    {
      const int rr = tid>>4, cc4 = (tid&15)*4;
#pragma unroll
      for (int i=0;i<4;i++){
        int r = i*16 + rr;
        float4 v = *(const float4*)&pin[(size_t)(r0+r)*C + c0 + cc4];
        t[cc4+0][r]=(bf16)v.x; t[cc4+1][r]=(bf16)v.y;
        t[cc4+2][r]=(bf16)v.z; t[cc4+3][r]=(bf16)v.w;
      }
    }
    __syncthreads();
    {
      const int rr8 = tid>>3, cc8 = (tid&7)*8;   // 32 rows/pass, 16B stores
#pragma unroll
      for (int i=0;i<2;i++){
        int c = i*32 + rr8;
        *(uint4*)&pout[(size_t)(c0+c)*R + r0 + cc8] = *(const uint4*)&t[c][cc8];
      }
    }
  }
}

// ---- fill: slot lists + per-token slot map (base computed inline from cnt) ----
__global__ __launch_bounds__(256) void k_fill(const float* __restrict__ disp,
    const float* __restrict__ comb, const float* __restrict__ scales,
    const int* __restrict__ cnt, int* __restrict__ fillc,
    int* __restrict__ stok, float* __restrict__ sw, int* __restrict__ sslot) {
  int m = blockIdx.x*256 + threadIdx.x;
  int base[NEXP]; int b = 0;
#pragma unroll
  for (int e=0;e<NEXP;e++){ base[e] = b; b += cnt[e]; }
  int jj = 0;
#pragma unroll
  for (int e=0;e<NEXP;e++){
    float dv = disp[(size_t)m*NEXP + e];
    if (dv > 0.f) {
      int s = atomicAdd(&fillc[e], 1);
      int g = base[e] + s;
      stok[g] = m;
      sw[g] = comb[(size_t)m*NEXP + e] * scales[e];
      if (jj < 2) sslot[m*2 + jj] = g;
      jj++;
    }
  }
}

// ---- GEMM1: H1 = gelu(X@Wg)*(X@Wv); 128M x 64N dual-B, BK=32, 32KB LDS ----
__global__ __launch_bounds__(256) void k_gemm1(const bf16* __restrict__ Xb,
    const bf16* __restrict__ WgT, const bf16* __restrict__ WvT,
    const int* __restrict__ cnt, const int* __restrict__ stok,
    bf16* __restrict__ H1) {
  int row0, nrows;
  if (!tile_map(cnt, blockIdx.y, row0, nrows)) return;
  const int e = expert_of(cnt, row0);
  const int n0 = blockIdx.x*64;
  __shared__ __align__(16) bf16 Al[2*128*32];   // 16 KB
  __shared__ __align__(16) bf16 Bgl[2*64*32];   // 8 KB
  __shared__ __align__(16) bf16 Bvl[2*64*32];   // 8 KB
  const int tid = threadIdx.x, lane = tid&63;
  const int wr = (tid>>7)&1, wc = (tid>>6)&1;
  const bf16* __restrict__ wg = WgT + (size_t)e*HID*DIM;  // [H][D], K contiguous
  const bf16* __restrict__ wv = WvT + (size_t)e*HID*DIM;

  const bf16* asrc[2];
#pragma unroll
  for (int i=0;i<2;i++){
    int c = i*256 + tid;
    int r = c>>2, qs = (c&3) ^ ((r>>1)&3);
    int gr = (r < nrows) ? (row0 + r) : row0;
    asrc[i] = Xb + (size_t)stok[gr]*DIM + qs*8;
  }
  const bf16 *bsg, *bsv;
  {
    int r = tid>>2, qs = (tid&3) ^ ((r>>1)&3);
    size_t o = (size_t)(n0 + r)*DIM + qs*8;
    bsg = wg + o; bsv = wv + o;
  }
  const int wbase = (tid&192)*8;

  auto stage = [&](int bi, int kt){
    const int k0 = kt*32;
    gload16(asrc[0]+k0, Al + bi*4096 + wbase);
    gload16(asrc[1]+k0, Al + bi*4096 + 2048 + wbase);
    gload16(bsg+k0, Bgl + bi*2048 + wbase);
    gload16(bsv+k0, Bvl + bi*2048 + wbase);
  };

  f32x4 accg[4][2] = {}, accv[4][2] = {};
  const int r15 = lane&15;
  const int koff = ((lane>>4) ^ ((r15>>1)&3))*8;
  stage(0, 0);
  for (int kt=0; kt<DIM/32; ++kt){
    const int bi = kt&1;
    if (kt+1 < DIM/32){ stage(bi^1, kt+1); WAITVM(4); }
    else WAITVM(0);
    BAR(); SCHED0;
    bf16x8 a[4], bg[2], bv[2];
#pragma unroll
    for (int ni=0; ni<2; ni++){
      bg[ni] = *(const bf16x8*)&Bgl[bi*2048 + (wc*32 + ni*16 + r15)*32 + koff];
      bv[ni] = *(const bf16x8*)&Bvl[bi*2048 + (wc*32 + ni*16 + r15)*32 + koff];
    }
#pragma unroll
    for (int mi=0; mi<4; mi++)
      a[mi] = *(const bf16x8*)&Al[bi*4096 + (wr*64 + mi*16 + r15)*32 + koff];
#pragma unroll
    for (int mi=0; mi<4; mi++)
#pragma unroll
      for (int ni=0; ni<2; ni++){
        accg[mi][ni] = __builtin_amdgcn_mfma_f32_16x16x32_bf16(a[mi], bg[ni], accg[mi][ni], 0,0,0);
        accv[mi][ni] = __builtin_amdgcn_mfma_f32_16x16x32_bf16(a[mi], bv[ni], accv[mi][ni], 0,0,0);
      }
    BAR(); SCHED0;
  }
  const int cb = n0 + wc*32 + r15;
  const int rb = wr*64 + (lane>>4)*4;
#pragma unroll
  for (int mi=0; mi<4; mi++)
#pragma unroll
    for (int j=0; j<4; j++){
      int r = rb + mi*16 + j;
      if (r < nrows){
#pragma unroll
        for (int ni=0; ni<2; ni++){
          float g = accg[mi][ni][j], v = accv[mi][ni][j];
          H1[(size_t)(row0+r)*HID + cb + ni*16] = (bf16)(gelu_f(g)*v);
        }
      }
    }
}

// ---- GEMM2: gout[slot] = (H1@Wo)*sw (bf16); 128x128, BK=32, XCD swizzle ----
__global__ __launch_bounds__(256) void k_gemm2(const bf16* __restrict__ H1,
    const bf16* __restrict__ WoT, const int* __restrict__ cnt,
    const float* __restrict__ sw, bf16* __restrict__ gout) {
  const int L = blockIdx.x;
  const int T = (L&7)*18 + (L>>5);     // bijective: 576 = 8 * (18 m x 4 n)
  const int n0 = ((L>>3)&3)*128;
  int row0, nrows;
  if (!tile_map(cnt, T, row0, nrows)) return;
  const int e = expert_of(cnt, row0);
  __shared__ __align__(16) bf16 Al[2*128*32];   // 16 KB
  __shared__ __align__(16) bf16 Bl[2*128*32];   // 16 KB
  const int tid = threadIdx.x, lane = tid&63;
  const int wr = (tid>>7)&1, wc = (tid>>6)&1;
  const bf16* __restrict__ wo = WoT + (size_t)e*DIM*HID;  // [D][H], K contiguous

  const bf16 *asrc[2], *bsrc[2];
#pragma unroll
  for (int i=0;i<2;i++){
    int c = i*256 + tid;
    int r = c>>2, qs = (c&3) ^ ((r>>1)&3);
    int ar = (r < nrows) ? (row0 + r) : row0;   // slot index (H1 is per-slot)
    asrc[i] = H1 + (size_t)ar*HID + qs*8;
    bsrc[i] = wo + (size_t)(n0 + r)*HID + qs*8;
  }
  const int wbase = (tid&192)*8;

  auto stage = [&](int bi, int kt){
    const int k0 = kt*32;
#pragma unroll
    for (int i=0;i<2;i++){
      gload16(asrc[i]+k0, Al + bi*4096 + i*2048 + wbase);
      gload16(bsrc[i]+k0, Bl + bi*4096 + i*2048 + wbase);
    }
  };

  f32x4 acc[4][4] = {};
  const int r15 = lane&15;
  const int koff = ((lane>>4) ^ ((r15>>1)&3))*8;
  stage(0, 0);
  for (int kt=0; kt<HID/32; ++kt){
    const int bi = kt&1;
    if (kt+1 < HID/32){ stage(bi^1, kt+1); WAITVM(4); }
    else WAITVM(0);
    BAR(); SCHED0;
    bf16x8 a[4], b[4];
#pragma unroll
    for (int ni=0; ni<4; ni++)
      b[ni] = *(const bf16x8*)&Bl[bi*4096 + (wc*64 + ni*16 + r15)*32 + koff];
#pragma unroll
    for (int mi=0; mi<4; mi++)
      a[mi] = *(const bf16x8*)&Al[bi*4096 + (wr*64 + mi*16 + r15)*32 + koff];
#pragma unroll
    for (int mi=0; mi<4; mi++)
#pragma unroll
      for (int ni=0; ni<4; ni++)
        acc[mi][ni] = __builtin_amdgcn_mfma_f32_16x16x32_bf16(a[mi], b[ni], acc[mi][ni], 0,0,0);
    BAR(); SCHED0;
  }
  const int cb = n0 + wc*64 + r15;
  const int rb = wr*64 + (lane>>4)*4;
#pragma unroll
  for (int mi=0; mi<4; mi++)
#pragma unroll
    for (int j=0; j<4; j++){
      int r = rb + mi*16 + j;
      if (r < nrows){
        int slot = row0 + r;
        float wgt = sw[slot];
        bf16* op = gout + (size_t)slot*DIM + cb;
#pragma unroll
        for (int ni=0; ni<4; ni++)
          op[ni*16] = (bf16)(acc[mi][ni][j] * wgt);   // bf16 store, no atomics
      }
    }
}

// ---- combine: out[tok] = gout[slot0] + gout[slot1] (bf16 in, fp32 out) ----
__global__ __launch_bounds__(256) void k_comb(const bf16* __restrict__ gout,
    const int* __restrict__ sslot, float* __restrict__ out) {
  int idx = blockIdx.x*256 + threadIdx.x;
  int m = idx >> 7, c4 = (idx & 127)*4;
  int s0 = sslot[m*2], s1 = sslot[m*2+1];
  const bf16* p0 = gout + (size_t)s0*DIM + c4;
  const bf16* p1 = gout + (size_t)s1*DIM + c4;
  bf16 a0[4], a1[4];
  *(uint2*)a0 = *(const uint2*)p0;
  *(uint2*)a1 = *(const uint2*)p1;
  float4 x;
  x.x = (float)a0[0] + (float)a1[0];
  x.y = (float)a0[1] + (float)a1[1];
  x.z = (float)a0[2] + (float)a1[2];
  x.w = (float)a0[3] + (float)a1[3];
  *(float4*)&out[(size_t)m*DIM + c4] = x;
}

extern "C" void kernel_launch(void* const* d_in, const int* in_sizes, int n_in,
                              void* d_out, int out_size, void* d_ws, size_t ws_size,
                              hipStream_t stream) {
  const float* tokens = (const float*)d_in[0];
  const float* disp   = (const float*)d_in[1];
  const float* comb   = (const float*)d_in[2];
  const float* Wg     = (const float*)d_in[3];
  const float* Wv     = (const float*)d_in[4];
  const float* Wo     = (const float*)d_in[5];
  const float* scales = (const float*)d_in[6];
  float* out = (float*)d_out;

  size_t off = 0;
  char* wsb = (char*)d_ws;
  auto take = [&](size_t bytes)->char* {
    char* q = wsb + off; off += (bytes + 255) & ~(size_t)255; return q;
  };
  int*   cnt   = (int*)  take(NEXP*4);
  int*   fillc = (int*)  take(NEXP*4);
  int*   stok  = (int*)  take((size_t)PMAX*4);
  float* sw    = (float*)take((size_t)PMAX*4);
  int*   sslot = (int*)  take((size_t)MTOK*2*4);
  bf16*  Xb    = (bf16*) take((size_t)MTOK*DIM*2);
  bf16*  WgT   = (bf16*) take((size_t)NEXP*DIM*HID*2);
  bf16*  WvT   = (bf16*) take((size_t)NEXP*DIM*HID*2);
  bf16*  WoT   = (bf16*) take((size_t)NEXP*DIM*HID*2);
  bf16*  H1    = (bf16*) take((size_t)PMAX*HID*2);
  // gout (bf16, 16 MiB) aliases WgT (dead after gemm1)
  bf16*  gout  = WgT;
  (void)ws_size; (void)in_sizes; (void)n_in; (void)out_size;

  k_prep <<<dim3(10241), 256, 0, stream>>>(tokens, Xb, Wg, Wv, Wo,
                                           WgT, WvT, WoT, disp, cnt, fillc);
  k_fill <<<dim3(MTOK/256), 256, 0, stream>>>(disp, comb, scales, cnt,
                                              fillc, stok, sw, sslot);
  k_gemm1<<<dim3(HID/64, MT), 256, 0, stream>>>(Xb, WgT, WvT, cnt, stok, H1);
  k_gemm2<<<dim3(8*18*4), 256, 0, stream>>>(H1, WoT, cnt, sw, gout);
  k_comb <<<dim3(MTOK*DIM/4/256), 256, 0, stream>>>(gout, sslot, out);
}

// Round 20
// 203.656 us; speedup vs baseline: 1.0208x; 1.0208x over previous
//
#include <hip/hip_runtime.h>
#include <hip/hip_bf16.h>

// MoE expert pool: E=8, D=512, H=2048, M=8192 tokens, top-2 routing.
// R20 = R18 byte-identical (best measured: 203.9us). R19's memset-elimination
// regressed (single-block count serialized prep); reverted.
// 6 dispatches: memset -> prep -> fill -> gemm1 -> gemm2 -> comb.
// gemm1: 128Mx64N dual-B BK32/32KB 2-phase dbuf (empirical fixed point over
// R4-R17's falsified alternatives), 2D grid N-slice L2 locality.
// gemm2: XCD-bijective, bf16 gout. Fast A-S gelu. Merged prep.

#define NEXP 8
#define DIM 512
#define HID 2048
#define MTOK 8192
#define PMAX (2*MTOK)
#define TM 128
#define MT 144

typedef __bf16 bf16;
typedef __bf16 bf16x8 __attribute__((ext_vector_type(8)));
typedef float  f32x4  __attribute__((ext_vector_type(4)));

#define WAITVM(N) asm volatile("s_waitcnt vmcnt(" #N ")" ::: "memory")
#define SCHED0    __builtin_amdgcn_sched_barrier(0)
#define BAR       __builtin_amdgcn_s_barrier

__device__ __forceinline__ void gload16(const bf16* g, bf16* l) {
  __builtin_amdgcn_global_load_lds(
      (const __attribute__((address_space(1))) void*)g,
      (__attribute__((address_space(3))) void*)l, 16, 0, 0);
}

// exact-gelu via Abramowitz-Stegun 7.1.26 erf (validated R10/R12).
__device__ __forceinline__ float gelu_f(float x){
  float s = x * 0.70710678118654752f;
  float a = fabsf(s);
  float t = 1.0f / fmaf(0.3275911f, a, 1.0f);
  float p = t*(0.254829592f + t*(-0.284496736f + t*(1.421413741f +
            t*(-1.453152027f + t*1.061405429f))));
  float er = 1.0f - p*__expf(-s*s);
  er = copysignf(er, s);
  return 0.5f*x*(1.0f + er);
}

// inline tile map: tile T -> (row0, nrows) from cnt[8] (validated R17/R18).
__device__ __forceinline__ bool tile_map(const int* __restrict__ cnt, int T,
                                         int& row0, int& nrows) {
  int sb = 0, stt = 0; bool ok = false;
#pragma unroll
  for (int q=0; q<NEXP; q++){
    int c = cnt[q];
    int nt = (c + TM-1)/TM;
    if (!ok && T >= stt && T < stt+nt){
      int k = T - stt;
      row0 = sb + k*TM;
      int nr = c - k*TM; if (nr > TM) nr = TM;
      nrows = nr; ok = true;
    }
    stt += nt; sb += c;
  }
  return ok;
}

// expert of slot row0 (prefix search, validated R17/R18).
__device__ __forceinline__ int expert_of(const int* __restrict__ cnt, int row0){
  int e = 0, b2 = 0;
#pragma unroll
  for (int q=0;q<NEXP;q++){ if (row0 >= b2 && row0 < b2+cnt[q]) e = q; b2 += cnt[q]; }
  return e;
}

// ---- merged prep: [0,4096) cvt_x | [4096,8192) WgWv tcvt | [8192,10240) Wo
// tcvt | [10240,10272) count. Transpose store phase = 16B/lane (R16).
__global__ __launch_bounds__(256) void k_prep(const float* __restrict__ tokens,
    bf16* __restrict__ Xb,
    const float* __restrict__ Wg, const float* __restrict__ Wv,
    const float* __restrict__ Wo,
    bf16* __restrict__ WgT, bf16* __restrict__ WvT, bf16* __restrict__ WoT,
    const float* __restrict__ disp, int* __restrict__ cnt) {
  __shared__ __align__(16) bf16 t[64][72];   // row stride 144B (16B-multiple)
  __shared__ int lc[NEXP];
  const int b = blockIdx.x, tid = threadIdx.x;

  if (b < 4096) {                       // ---- fp32 -> bf16 tokens ----
    int i = b*256 + tid;                // n4 = 1048576 = 4096*256 exact
    float4 v = ((const float4* __restrict__)tokens)[i];
    bf16 o[4];
    o[0]=(bf16)v.x; o[1]=(bf16)v.y; o[2]=(bf16)v.z; o[3]=(bf16)v.w;
    *(uint2*)&Xb[(size_t)i*4] = *(uint2*)o;
    return;
  }
  if (b < 10240) {                      // ---- transpose+convert ----
    const float* pin; bf16* pout; int R, C, c0, r0;
    if (b < 8192) {                     // WgWv: (32,8,16), R=DIM, C=HID
      int u = b - 4096;
      int bx = u&31, by = (u>>5)&7, z = u>>8;
      int e = z & (NEXP-1);
      pin  = ((z < NEXP) ? Wg : Wv) + (size_t)e*DIM*HID;
      pout = ((z < NEXP) ? WgT : WvT) + (size_t)e*DIM*HID;
      R = DIM; C = HID; c0 = bx*64; r0 = by*64;
    } else {                            // Wo: (8,32,8), R=HID, C=DIM
      int u = b - 8192;
      int bx = u&7, by = (u>>3)&31, z = u>>8;
      pin  = Wo  + (size_t)z*HID*DIM;
      pout = WoT + (size_t)z*HID*DIM;
      R = HID; C = DIM; c0 = bx*64; r0 = by*64;
    }
    {
      const int rr = tid>>4, cc4 = (tid&15)*4;
#pragma unroll
      for (int i=0;i<4;i++){
        int r = i*16 + rr;
        float4 v = *(const float4*)&pin[(size_t)(r0+r)*C + c0 + cc4];
        t[cc4+0][r]=(bf16)v.x; t[cc4+1][r]=(bf16)v.y;
        t[cc4+2][r]=(bf16)v.z; t[cc4+3][r]=(bf16)v.w;
      }
    }
    __syncthreads();
    {
      const int rr8 = tid>>3, cc8 = (tid&7)*8;   // 32 rows/pass, 16B stores
#pragma unroll
      for (int i=0;i<2;i++){
        int c = i*32 + rr8;
        *(uint4*)&pout[(size_t)(c0+c)*R + r0 + cc8] = *(const uint4*)&t[c][cc8];
      }
    }
    return;
  }
  {                                     // ---- count tokens per expert ----
    if (tid < NEXP) lc[tid] = 0;
    __syncthreads();
    int m = (b - 10240)*256 + tid;
    float4 d0 = *(const float4*)&disp[(size_t)m*NEXP];
    float4 d1 = *(const float4*)&disp[(size_t)m*NEXP+4];
    if (d0.x>0.f) atomicAdd(&lc[0],1);
    if (d0.y>0.f) atomicAdd(&lc[1],1);
    if (d0.z>0.f) atomicAdd(&lc[2],1);
    if (d0.w>0.f) atomicAdd(&lc[3],1);
    if (d1.x>0.f) atomicAdd(&lc[4],1);
    if (d1.y>0.f) atomicAdd(&lc[5],1);
    if (d1.z>0.f) atomicAdd(&lc[6],1);
    if (d1.w>0.f) atomicAdd(&lc[7],1);
    __syncthreads();
    if (tid < NEXP) atomicAdd(&cnt[tid], lc[tid]);
  }
}

// ---- fill: slot lists + per-token slot map (base computed inline from cnt) ----
__global__ __launch_bounds__(256) void k_fill(const float* __restrict__ disp,
    const float* __restrict__ comb, const float* __restrict__ scales,
    const int* __restrict__ cnt, int* __restrict__ fillc,
    int* __restrict__ stok, float* __restrict__ sw, int* __restrict__ sslot) {
  int m = blockIdx.x*256 + threadIdx.x;
  int base[NEXP]; int b = 0;
#pragma unroll
  for (int e=0;e<NEXP;e++){ base[e] = b; b += cnt[e]; }
  int jj = 0;
#pragma unroll
  for (int e=0;e<NEXP;e++){
    float dv = disp[(size_t)m*NEXP + e];
    if (dv > 0.f) {
      int s = atomicAdd(&fillc[e], 1);
      int g = base[e] + s;
      stok[g] = m;
      sw[g] = comb[(size_t)m*NEXP + e] * scales[e];
      if (jj < 2) sslot[m*2 + jj] = g;
      jj++;
    }
  }
}

// ---- GEMM1: H1 = gelu(X@Wg)*(X@Wv); 128M x 64N dual-B, BK=32, 32KB LDS ----
__global__ __launch_bounds__(256) void k_gemm1(const bf16* __restrict__ Xb,
    const bf16* __restrict__ WgT, const bf16* __restrict__ WvT,
    const int* __restrict__ cnt, const int* __restrict__ stok,
    bf16* __restrict__ H1) {
  int row0, nrows;
  if (!tile_map(cnt, blockIdx.y, row0, nrows)) return;
  const int e = expert_of(cnt, row0);
  const int n0 = blockIdx.x*64;
  __shared__ __align__(16) bf16 Al[2*128*32];   // 16 KB
  __shared__ __align__(16) bf16 Bgl[2*64*32];   // 8 KB
  __shared__ __align__(16) bf16 Bvl[2*64*32];   // 8 KB
  const int tid = threadIdx.x, lane = tid&63;
  const int wr = (tid>>7)&1, wc = (tid>>6)&1;
  const bf16* __restrict__ wg = WgT + (size_t)e*HID*DIM;  // [H][D], K contiguous
  const bf16* __restrict__ wv = WvT + (size_t)e*HID*DIM;

  const bf16* asrc[2];
#pragma unroll
  for (int i=0;i<2;i++){
    int c = i*256 + tid;
    int r = c>>2, qs = (c&3) ^ ((r>>1)&3);
    int gr = (r < nrows) ? (row0 + r) : row0;
    asrc[i] = Xb + (size_t)stok[gr]*DIM + qs*8;
  }
  const bf16 *bsg, *bsv;
  {
    int r = tid>>2, qs = (tid&3) ^ ((r>>1)&3);
    size_t o = (size_t)(n0 + r)*DIM + qs*8;
    bsg = wg + o; bsv = wv + o;
  }
  const int wbase = (tid&192)*8;

  auto stage = [&](int bi, int kt){
    const int k0 = kt*32;
    gload16(asrc[0]+k0, Al + bi*4096 + wbase);
    gload16(asrc[1]+k0, Al + bi*4096 + 2048 + wbase);
    gload16(bsg+k0, Bgl + bi*2048 + wbase);
    gload16(bsv+k0, Bvl + bi*2048 + wbase);
  };

  f32x4 accg[4][2] = {}, accv[4][2] = {};
  const int r15 = lane&15;
  const int koff = ((lane>>4) ^ ((r15>>1)&3))*8;
  stage(0, 0);
  for (int kt=0; kt<DIM/32; ++kt){
    const int bi = kt&1;
    if (kt+1 < DIM/32){ stage(bi^1, kt+1); WAITVM(4); }
    else WAITVM(0);
    BAR(); SCHED0;
    bf16x8 a[4], bg[2], bv[2];
#pragma unroll
    for (int ni=0; ni<2; ni++){
      bg[ni] = *(const bf16x8*)&Bgl[bi*2048 + (wc*32 + ni*16 + r15)*32 + koff];
      bv[ni] = *(const bf16x8*)&Bvl[bi*2048 + (wc*32 + ni*16 + r15)*32 + koff];
    }
#pragma unroll
    for (int mi=0; mi<4; mi++)
      a[mi] = *(const bf16x8*)&Al[bi*4096 + (wr*64 + mi*16 + r15)*32 + koff];
#pragma unroll
    for (int mi=0; mi<4; mi++)
#pragma unroll
      for (int ni=0; ni<2; ni++){
        accg[mi][ni] = __builtin_amdgcn_mfma_f32_16x16x32_bf16(a[mi], bg[ni], accg[mi][ni], 0,0,0);
        accv[mi][ni] = __builtin_amdgcn_mfma_f32_16x16x32_bf16(a[mi], bv[ni], accv[mi][ni], 0,0,0);
      }
    BAR(); SCHED0;
  }
  const int cb = n0 + wc*32 + r15;
  const int rb = wr*64 + (lane>>4)*4;
#pragma unroll
  for (int mi=0; mi<4; mi++)
#pragma unroll
    for (int j=0; j<4; j++){
      int r = rb + mi*16 + j;
      if (r < nrows){
#pragma unroll
        for (int ni=0; ni<2; ni++){
          float g = accg[mi][ni][j], v = accv[mi][ni][j];
          H1[(size_t)(row0+r)*HID + cb + ni*16] = (bf16)(gelu_f(g)*v);
        }
      }
    }
}

// ---- GEMM2: gout[slot] = (H1@Wo)*sw (bf16); 128x128, BK=32, XCD swizzle ----
__global__ __launch_bounds__(256) void k_gemm2(const bf16* __restrict__ H1,
    const bf16* __restrict__ WoT, const int* __restrict__ cnt,
    const float* __restrict__ sw, bf16* __restrict__ gout) {
  const int L = blockIdx.x;
  const int T = (L&7)*18 + (L>>5);     // bijective: 576 = 8 * (18 m x 4 n)
  const int n0 = ((L>>3)&3)*128;
  int row0, nrows;
  if (!tile_map(cnt, T, row0, nrows)) return;
  const int e = expert_of(cnt, row0);
  __shared__ __align__(16) bf16 Al[2*128*32];   // 16 KB
  __shared__ __align__(16) bf16 Bl[2*128*32];   // 16 KB
  const int tid = threadIdx.x, lane = tid&63;
  const int wr = (tid>>7)&1, wc = (tid>>6)&1;
  const bf16* __restrict__ wo = WoT + (size_t)e*DIM*HID;  // [D][H], K contiguous

  const bf16 *asrc[2], *bsrc[2];
#pragma unroll
  for (int i=0;i<2;i++){
    int c = i*256 + tid;
    int r = c>>2, qs = (c&3) ^ ((r>>1)&3);
    int ar = (r < nrows) ? (row0 + r) : row0;   // slot index (H1 is per-slot)
    asrc[i] = H1 + (size_t)ar*HID + qs*8;
    bsrc[i] = wo + (size_t)(n0 + r)*HID + qs*8;
  }
  const int wbase = (tid&192)*8;

  auto stage = [&](int bi, int kt){
    const int k0 = kt*32;
#pragma unroll
    for (int i=0;i<2;i++){
      gload16(asrc[i]+k0, Al + bi*4096 + i*2048 + wbase);
      gload16(bsrc[i]+k0, Bl + bi*4096 + i*2048 + wbase);
    }
  };

  f32x4 acc[4][4] = {};
  const int r15 = lane&15;
  const int koff = ((lane>>4) ^ ((r15>>1)&3))*8;
  stage(0, 0);
  for (int kt=0; kt<HID/32; ++kt){
    const int bi = kt&1;
    if (kt+1 < HID/32){ stage(bi^1, kt+1); WAITVM(4); }
    else WAITVM(0);
    BAR(); SCHED0;
    bf16x8 a[4], b[4];
#pragma unroll
    for (int ni=0; ni<4; ni++)
      b[ni] = *(const bf16x8*)&Bl[bi*4096 + (wc*64 + ni*16 + r15)*32 + koff];
#pragma unroll
    for (int mi=0; mi<4; mi++)
      a[mi] = *(const bf16x8*)&Al[bi*4096 + (wr*64 + mi*16 + r15)*32 + koff];
#pragma unroll
    for (int mi=0; mi<4; mi++)
#pragma unroll
      for (int ni=0; ni<4; ni++)
        acc[mi][ni] = __builtin_amdgcn_mfma_f32_16x16x32_bf16(a[mi], b[ni], acc[mi][ni], 0,0,0);
    BAR(); SCHED0;
  }
  const int cb = n0 + wc*64 + r15;
  const int rb = wr*64 + (lane>>4)*4;
#pragma unroll
  for (int mi=0; mi<4; mi++)
#pragma unroll
    for (int j=0; j<4; j++){
      int r = rb + mi*16 + j;
      if (r < nrows){
        int slot = row0 + r;
        float wgt = sw[slot];
        bf16* op = gout + (size_t)slot*DIM + cb;
#pragma unroll
        for (int ni=0; ni<4; ni++)
          op[ni*16] = (bf16)(acc[mi][ni][j] * wgt);   // bf16 store, no atomics
      }
    }
}

// ---- combine: out[tok] = gout[slot0] + gout[slot1] (bf16 in, fp32 out) ----
__global__ __launch_bounds__(256) void k_comb(const bf16* __restrict__ gout,
    const int* __restrict__ sslot, float* __restrict__ out) {
  int idx = blockIdx.x*256 + threadIdx.x;
  int m = idx >> 7, c4 = (idx & 127)*4;
  int s0 = sslot[m*2], s1 = sslot[m*2+1];
  const bf16* p0 = gout + (size_t)s0*DIM + c4;
  const bf16* p1 = gout + (size_t)s1*DIM + c4;
  bf16 a0[4], a1[4];
  *(uint2*)a0 = *(const uint2*)p0;
  *(uint2*)a1 = *(const uint2*)p1;
  float4 x;
  x.x = (float)a0[0] + (float)a1[0];
  x.y = (float)a0[1] + (float)a1[1];
  x.z = (float)a0[2] + (float)a1[2];
  x.w = (float)a0[3] + (float)a1[3];
  *(float4*)&out[(size_t)m*DIM + c4] = x;
}

extern "C" void kernel_launch(void* const* d_in, const int* in_sizes, int n_in,
                              void* d_out, int out_size, void* d_ws, size_t ws_size,
                              hipStream_t stream) {
  const float* tokens = (const float*)d_in[0];
  const float* disp   = (const float*)d_in[1];
  const float* comb   = (const float*)d_in[2];
  const float* Wg     = (const float*)d_in[3];
  const float* Wv     = (const float*)d_in[4];
  const float* Wo     = (const float*)d_in[5];
  const float* scales = (const float*)d_in[6];
  float* out = (float*)d_out;

  size_t off = 0;
  char* wsb = (char*)d_ws;
  auto take = [&](size_t bytes)->char* {
    char* q = wsb + off; off += (bytes + 255) & ~(size_t)255; return q;
  };
  int*   cnt   = (int*)  take(NEXP*4);
  int*   fillc = (int*)  take(NEXP*4);
  int*   stok  = (int*)  take((size_t)PMAX*4);
  float* sw    = (float*)take((size_t)PMAX*4);
  int*   sslot = (int*)  take((size_t)MTOK*2*4);
  bf16*  Xb    = (bf16*) take((size_t)MTOK*DIM*2);
  bf16*  WgT   = (bf16*) take((size_t)NEXP*DIM*HID*2);
  bf16*  WvT   = (bf16*) take((size_t)NEXP*DIM*HID*2);
  bf16*  WoT   = (bf16*) take((size_t)NEXP*DIM*HID*2);
  bf16*  H1    = (bf16*) take((size_t)PMAX*HID*2);
  // gout (bf16, 16 MiB) aliases WgT (dead after gemm1)
  bf16*  gout  = WgT;
  (void)ws_size; (void)in_sizes; (void)n_in; (void)out_size;

  hipMemsetAsync(d_ws, 0, 512, stream);   // cnt + fillc

  k_prep <<<dim3(10272), 256, 0, stream>>>(tokens, Xb, Wg, Wv, Wo,
                                           WgT, WvT, WoT, disp, cnt);
  k_fill <<<dim3(MTOK/256), 256, 0, stream>>>(disp, comb, scales, cnt,
                                              fillc, stok, sw, sslot);
  k_gemm1<<<dim3(HID/64, MT), 256, 0, stream>>>(Xb, WgT, WvT, cnt, stok, H1);
  k_gemm2<<<dim3(8*18*4), 256, 0, stream>>>(H1, WoT, cnt, sw, gout);
  k_comb <<<dim3(MTOK*DIM/4/256), 256, 0, stream>>>(gout, sslot, out);
}